// Round 7
// baseline (219.581 us; speedup 1.0000x reference)
//
#include <hip/hip_runtime.h>
#include <hip/hip_bf16.h>

#define IN_FEAT 128
#define N_HEADS 4
#define OUT_FEAT 16
#define HF 64  // N_HEADS * OUT_FEAT
#define NEG_SLOPE 0.2f

typedef __hip_bfloat16 bf16;
typedef __attribute__((ext_vector_type(8))) short short8;
typedef __attribute__((ext_vector_type(4))) float f32x4;

__device__ inline unsigned short f2b(float f) {
  bf16 b = __float2bfloat16(f);
  return *(unsigned short*)&b;
}
__device__ inline float b2f(unsigned short u) {
  return __uint_as_float((unsigned)u << 16);
}

// ---------------------------------------------------------------------------
// Prep: Wt[c][k] = bf16(W[k][c]) — 16 KB, L1/L2-resident for k_gemm B-frags.
// ---------------------------------------------------------------------------
__global__ __launch_bounds__(256) void k_wprep(
    const float* __restrict__ W, unsigned short* __restrict__ Wt) {
  int i = blockIdx.x * 256 + threadIdx.x;   // 32 blocks x 256 = 8192
  int k = i >> 6, c = i & 63;
  Wt[c * IN_FEAT + k] = f2b(W[i]);
}

// ---------------------------------------------------------------------------
// Kernel 1: h = x @ W via bf16 MFMA. Block = 256 thr = 4 waves = 64 nodes.
// B-fragments come straight from global Wt (16 KB, cache-hot) — no wt LDS,
// no transpose bank conflicts. LDS: xs 17.4 KB + sh 8.7 KB = 26.1 KB
// -> ~6 blocks/CU (vs 3 before) for latency hiding.
// Fragment layouts (m89/m120): A[m=lane&15][k=(lane>>4)*8+j],
// B[k=(lane>>4)*8+j][n=lane&15] = Wt[n][k..k+8), D col=lane&15 row=q*4+reg.
// ---------------------------------------------------------------------------
__global__ __launch_bounds__(256) void k_gemm(
    const float* __restrict__ x, const unsigned short* __restrict__ Wt,
    const float* __restrict__ a, unsigned short* __restrict__ h16,
    float* __restrict__ e_src, float* __restrict__ e_dst, int n_nodes) {
  __shared__ unsigned short xs[64][136];
  __shared__ unsigned short sh[64][68];
  const int t = threadIdx.x;
  const int nb = blockIdx.x * 64;
  const int lane = t & 63;
  const int w = t >> 6;

  const float4* x4 = (const float4*)x;
  for (int i = t; i < 64 * 32; i += 256) {
    int n = i >> 5, k4 = i & 31;
    int gn = nb + n;
    float4 v = (gn < n_nodes) ? x4[(size_t)gn * 32 + k4]
                              : make_float4(0.f, 0.f, 0.f, 0.f);
    ushort4 u;
    u.x = f2b(v.x); u.y = f2b(v.y); u.z = f2b(v.z); u.w = f2b(v.w);
    *(ushort4*)&xs[n][k4 * 4] = u;
  }
  __syncthreads();

  const int m = lane & 15;
  const int q = lane >> 4;
  f32x4 acc[4];
#pragma unroll
  for (int nt = 0; nt < 4; ++nt) acc[nt] = (f32x4){0.f, 0.f, 0.f, 0.f};

#pragma unroll
  for (int kc = 0; kc < 4; ++kc) {
    short8 af = *(const short8*)&xs[w * 16 + m][kc * 32 + q * 8];
#pragma unroll
    for (int nt = 0; nt < 4; ++nt) {
      short8 bfr = *(const short8*)&Wt[(nt * 16 + m) * IN_FEAT + kc * 32 + q * 8];
      acc[nt] = __builtin_amdgcn_mfma_f32_16x16x32_bf16(af, bfr, acc[nt], 0, 0, 0);
    }
  }

#pragma unroll
  for (int nt = 0; nt < 4; ++nt)
#pragma unroll
    for (int r = 0; r < 4; ++r)
      sh[w * 16 + q * 4 + r][nt * 16 + m] = f2b(acc[nt][r]);
  __syncthreads();

  {
    int n = t >> 2, hd = t & 3;
    int gn = nb + n;
    if (gn < n_nodes) {
      float es = 0.f, ed = 0.f;
#pragma unroll
      for (int f = 0; f < OUT_FEAT; ++f) {
        float hv = b2f(sh[n][hd * 16 + f]);
        es = fmaf(hv, a[hd * 2 * OUT_FEAT + f], es);
        ed = fmaf(hv, a[hd * 2 * OUT_FEAT + OUT_FEAT + f], ed);
      }
      e_src[gn * N_HEADS + hd] = es;
      e_dst[gn * N_HEADS + hd] = ed;
    }
  }

  for (int i = t; i < 64 * 16; i += 256) {
    int n = i >> 4, c4 = (i & 15) * 4;
    int gn = nb + n;
    if (gn < n_nodes) {
      ushort4 v;
      v.x = sh[n][c4 + 0]; v.y = sh[n][c4 + 1];
      v.z = sh[n][c4 + 2]; v.w = sh[n][c4 + 3];
      *(ushort4*)(h16 + (size_t)gn * HF + c4) = v;
    }
  }
}

// ---------------------------------------------------------------------------
// Histogram of dst (separate kernel for profile visibility).
// ---------------------------------------------------------------------------
__global__ __launch_bounds__(256) void k_hist(
    const int* __restrict__ dst, int* __restrict__ counts, int n_edges) {
  int e = blockIdx.x * 256 + threadIdx.x;
  if (e < n_edges) atomicAdd(&counts[dst[e]], 1);
}

// ---------------------------------------------------------------------------
// 3-kernel coalesced scan: tile sums -> scan sums -> apply.
// ---------------------------------------------------------------------------
__global__ __launch_bounds__(256) void k_scan1(
    const int* __restrict__ counts, int* __restrict__ partial, int n) {
  __shared__ int s[256];
  int t = threadIdx.x;
  int i = blockIdx.x * 256 + t;
  s[t] = (i < n) ? counts[i] : 0;
  __syncthreads();
  for (int off = 128; off > 0; off >>= 1) {
    if (t < off) s[t] += s[t + off];
    __syncthreads();
  }
  if (t == 0) partial[blockIdx.x] = s[0];
}

__global__ __launch_bounds__(256) void k_scan2(int* __restrict__ partial, int nb) {
  __shared__ int s[256];
  int t = threadIdx.x;
  s[t] = (t < nb) ? partial[t] : 0;
  __syncthreads();
  for (int off = 1; off < 256; off <<= 1) {
    int v = (t >= off) ? s[t - off] : 0;
    __syncthreads();
    s[t] += v;
    __syncthreads();
  }
  if (t < nb) partial[t] = (t == 0) ? 0 : s[t - 1];
}

__global__ __launch_bounds__(256) void k_scan3(
    const int* __restrict__ counts, const int* __restrict__ partial,
    int* __restrict__ offsets, int* __restrict__ cursor, int n, int n_edges) {
  __shared__ int s[256];
  int t = threadIdx.x;
  int i = blockIdx.x * 256 + t;
  int v = (i < n) ? counts[i] : 0;
  s[t] = v;
  __syncthreads();
  for (int off = 1; off < 256; off <<= 1) {
    int u = (t >= off) ? s[t - off] : 0;
    __syncthreads();
    s[t] += u;
    __syncthreads();
  }
  int excl = s[t] - v + partial[blockIdx.x];
  if (i < n) {
    offsets[i] = excl;
    cursor[i] = excl;
  }
  if (i == 0) offsets[n] = n_edges;
}

// ---------------------------------------------------------------------------
// Reorder + per-edge softmax: ONE 16-byte record per edge {src, a01, a23, 0}
// -> single scattered dwordx4 store (one 64B line/edge, not two).
// ---------------------------------------------------------------------------
__global__ __launch_bounds__(256) void k_reorder(
    const int* __restrict__ src, const int* __restrict__ dst,
    const float* __restrict__ e_src, const float* __restrict__ e_dst,
    int* __restrict__ cursor, int4* __restrict__ recs, int n_edges) {
  int e = blockIdx.x * 256 + threadIdx.x;
  if (e >= n_edges) return;
  int s = src[e], d = dst[e];
  float4 es = ((const float4*)e_src)[s];
  float4 ed = ((const float4*)e_dst)[d];
  float v0 = es.x + ed.x, v1 = es.y + ed.y, v2 = es.z + ed.z, v3 = es.w + ed.w;
  v0 = (v0 > 0.f) ? v0 : NEG_SLOPE * v0;
  v1 = (v1 > 0.f) ? v1 : NEG_SLOPE * v1;
  v2 = (v2 > 0.f) ? v2 : NEG_SLOPE * v2;
  v3 = (v3 > 0.f) ? v3 : NEG_SLOPE * v3;
  float m = fmaxf(fmaxf(v0, v1), fmaxf(v2, v3));
  float e0 = __expf(v0 - m), e1 = __expf(v1 - m);
  float e2 = __expf(v2 - m), e3 = __expf(v3 - m);
  float inv = 1.f / (e0 + e1 + e2 + e3);
  int a01 = (int)((unsigned)f2b(e0 * inv) | ((unsigned)f2b(e1 * inv) << 16));
  int a23 = (int)((unsigned)f2b(e2 * inv) | ((unsigned)f2b(e3 * inv) << 16));
  int pos = atomicAdd(&cursor[d], 1);
  recs[pos] = make_int4(s, a01, a23, 0);
}

// ---------------------------------------------------------------------------
// Gather: one wave per dst node, lane = feature. Per edge: one broadcast
// dwordx4 record + one gathered ushort h16 + extract + fma. Unroll x8.
// ---------------------------------------------------------------------------
__global__ __launch_bounds__(256) void k_gather(
    const int4* __restrict__ recs, const int* __restrict__ offsets,
    const unsigned short* __restrict__ h16, float* __restrict__ out,
    int n_nodes) {
  int gid = blockIdx.x * 256 + threadIdx.x;
  int d = gid >> 6;
  int c = gid & 63;
  if (d >= n_nodes) return;
  int beg = offsets[d];
  int end = offsets[d + 1];
  const bool hiword = (c & 32) != 0;     // heads 2,3 in .z
  const unsigned shamt = (c & 16) ? 16 : 0;
  float acc = 0.f;
  int j = beg;
  for (; j + 8 <= end; j += 8) {
    int4 r[8];
    float hv[8];
#pragma unroll
    for (int k = 0; k < 8; ++k) r[k] = recs[j + k];
#pragma unroll
    for (int k = 0; k < 8; ++k) hv[k] = b2f(h16[(size_t)r[k].x * HF + c]);
#pragma unroll
    for (int k = 0; k < 8; ++k) {
      unsigned aw = (unsigned)(hiword ? r[k].z : r[k].y);
      float al = __uint_as_float(((aw >> shamt) & 0xFFFFu) << 16);
      acc = fmaf(al, hv[k], acc);
    }
  }
  for (; j < end; ++j) {
    int4 r = recs[j];
    float hv = b2f(h16[(size_t)r.x * HF + c]);
    unsigned aw = (unsigned)(hiword ? r.z : r.y);
    float al = __uint_as_float(((aw >> shamt) & 0xFFFFu) << 16);
    acc = fmaf(al, hv, acc);
  }
  out[(size_t)d * HF + c] = acc;
}

extern "C" void kernel_launch(void* const* d_in, const int* in_sizes, int n_in,
                              void* d_out, int out_size, void* d_ws, size_t ws_size,
                              hipStream_t stream) {
  const float* x = (const float*)d_in[0];
  const int* ei = (const int*)d_in[1];
  const float* W = (const float*)d_in[2];
  const float* a = (const float*)d_in[3];
  float* out = (float*)d_out;

  const int n_nodes = in_sizes[0] / IN_FEAT;   // 50000
  const int n_edges = in_sizes[1] / 2;         // 800000
  const int* src = ei;
  const int* dst = ei + n_edges;

  char* ws = (char*)d_ws;
  size_t off = 0;
  unsigned short* h16 = (unsigned short*)(ws + off); off += (size_t)n_nodes * HF * 2;  // 6.4 MB
  int4* recs = (int4*)(ws + off);         off += (size_t)n_edges * 16;                 // 12.8 MB
  float* e_src = (float*)(ws + off);      off += (size_t)n_nodes * N_HEADS * 4;        // 0.8 MB
  float* e_dst = (float*)(ws + off);      off += (size_t)n_nodes * N_HEADS * 4;        // 0.8 MB
  unsigned short* Wt = (unsigned short*)(ws + off); off += (size_t)IN_FEAT * HF * 2;   // 16 KB
  int* counts = (int*)(ws + off);         off += ((size_t)n_nodes + 16) * 4;
  int* offsets = (int*)(ws + off);        off += ((size_t)n_nodes + 16) * 4;
  int* cursor = (int*)(ws + off);         off += ((size_t)n_nodes + 16) * 4;
  int* partial = (int*)(ws + off);        off += 256 * 4;

  const int nb_nodes = (n_nodes + 255) / 256;  // 196 <= 256 (k_scan2 limit)
  const int nb_edges = (n_edges + 255) / 256;

  hipMemsetAsync(counts, 0, (size_t)n_nodes * 4, stream);
  k_wprep<<<IN_FEAT * HF / 256, 256, 0, stream>>>(W, Wt);
  k_hist<<<nb_edges, 256, 0, stream>>>(dst, counts, n_edges);
  k_gemm<<<(n_nodes + 63) / 64, 256, 0, stream>>>(
      x, Wt, a, h16, e_src, e_dst, n_nodes);
  k_scan1<<<nb_nodes, 256, 0, stream>>>(counts, partial, n_nodes);
  k_scan2<<<1, 256, 0, stream>>>(partial, nb_nodes);
  k_scan3<<<nb_nodes, 256, 0, stream>>>(counts, partial, offsets, cursor, n_nodes, n_edges);
  k_reorder<<<nb_edges, 256, 0, stream>>>(
      src, dst, e_src, e_dst, cursor, recs, n_edges);
  k_gather<<<(n_nodes * 64 + 255) / 256, 256, 0, stream>>>(
      recs, offsets, h16, out, n_nodes);
}

// Round 8
// 216.855 us; speedup vs baseline: 1.0126x; 1.0126x over previous
//
#include <hip/hip_runtime.h>
#include <hip/hip_bf16.h>

#define IN_FEAT 128
#define N_HEADS 4
#define OUT_FEAT 16
#define HF 64  // N_HEADS * OUT_FEAT
#define NEG_SLOPE 0.2f
#define NRANGE 8   // dst-space buckets ~ XCD count

typedef __hip_bfloat16 bf16;
typedef __attribute__((ext_vector_type(8))) short short8;
typedef __attribute__((ext_vector_type(4))) float f32x4;

__device__ inline unsigned short f2b(float f) {
  bf16 b = __float2bfloat16(f);
  return *(unsigned short*)&b;
}
__device__ inline float b2f(unsigned short u) {
  return __uint_as_float((unsigned)u << 16);
}

// ---------------------------------------------------------------------------
// Prep: Wt[c][k] = bf16(W[k][c]) — 16 KB, cache-resident for k_gemm B-frags.
// ---------------------------------------------------------------------------
__global__ __launch_bounds__(256) void k_wprep(
    const float* __restrict__ W, unsigned short* __restrict__ Wt) {
  int i = blockIdx.x * 256 + threadIdx.x;   // 32 blocks x 256 = 8192
  int k = i >> 6, c = i & 63;
  Wt[c * IN_FEAT + k] = f2b(W[i]);
}

// ---------------------------------------------------------------------------
// Kernel 1: h = x @ W via bf16 MFMA. Block = 256 thr = 4 waves = 64 nodes.
// B-frags straight from global Wt (16 KB, cache-hot). LDS 26.1 KB.
// ---------------------------------------------------------------------------
__global__ __launch_bounds__(256) void k_gemm(
    const float* __restrict__ x, const unsigned short* __restrict__ Wt,
    const float* __restrict__ a, unsigned short* __restrict__ h16,
    float* __restrict__ e_src, float* __restrict__ e_dst, int n_nodes) {
  __shared__ unsigned short xs[64][136];
  __shared__ unsigned short sh[64][68];
  const int t = threadIdx.x;
  const int nb = blockIdx.x * 64;
  const int lane = t & 63;
  const int w = t >> 6;

  const float4* x4 = (const float4*)x;
  for (int i = t; i < 64 * 32; i += 256) {
    int n = i >> 5, k4 = i & 31;
    int gn = nb + n;
    float4 v = (gn < n_nodes) ? x4[(size_t)gn * 32 + k4]
                              : make_float4(0.f, 0.f, 0.f, 0.f);
    ushort4 u;
    u.x = f2b(v.x); u.y = f2b(v.y); u.z = f2b(v.z); u.w = f2b(v.w);
    *(ushort4*)&xs[n][k4 * 4] = u;
  }
  __syncthreads();

  const int m = lane & 15;
  const int q = lane >> 4;
  f32x4 acc[4];
#pragma unroll
  for (int nt = 0; nt < 4; ++nt) acc[nt] = (f32x4){0.f, 0.f, 0.f, 0.f};

#pragma unroll
  for (int kc = 0; kc < 4; ++kc) {
    short8 af = *(const short8*)&xs[w * 16 + m][kc * 32 + q * 8];
#pragma unroll
    for (int nt = 0; nt < 4; ++nt) {
      short8 bfr = *(const short8*)&Wt[(nt * 16 + m) * IN_FEAT + kc * 32 + q * 8];
      acc[nt] = __builtin_amdgcn_mfma_f32_16x16x32_bf16(af, bfr, acc[nt], 0, 0, 0);
    }
  }

#pragma unroll
  for (int nt = 0; nt < 4; ++nt)
#pragma unroll
    for (int r = 0; r < 4; ++r)
      sh[w * 16 + q * 4 + r][nt * 16 + m] = f2b(acc[nt][r]);
  __syncthreads();

  {
    int n = t >> 2, hd = t & 3;
    int gn = nb + n;
    if (gn < n_nodes) {
      float es = 0.f, ed = 0.f;
#pragma unroll
      for (int f = 0; f < OUT_FEAT; ++f) {
        float hv = b2f(sh[n][hd * 16 + f]);
        es = fmaf(hv, a[hd * 2 * OUT_FEAT + f], es);
        ed = fmaf(hv, a[hd * 2 * OUT_FEAT + OUT_FEAT + f], ed);
      }
      e_src[gn * N_HEADS + hd] = es;
      e_dst[gn * N_HEADS + hd] = ed;
    }
  }

  for (int i = t; i < 64 * 16; i += 256) {
    int n = i >> 4, c4 = (i & 15) * 4;
    int gn = nb + n;
    if (gn < n_nodes) {
      ushort4 v;
      v.x = sh[n][c4 + 0]; v.y = sh[n][c4 + 1];
      v.z = sh[n][c4 + 2]; v.w = sh[n][c4 + 3];
      *(ushort4*)(h16 + (size_t)gn * HF + c4) = v;
    }
  }
}

// ---------------------------------------------------------------------------
// Histogram, XCD-bucketed: block = (chunk = blockIdx>>3, range = blockIdx&7).
// Each block streams its 1024-edge chunk, counts only dst in its range.
// Range r's blocks land on XCD r (blockIdx%8 round-robin) -> counts slice
// stays in that XCD's L2 -> no cross-XCD atomic line ping-pong.
// ---------------------------------------------------------------------------
__global__ __launch_bounds__(256) void k_hist(
    const int* __restrict__ dst, int* __restrict__ counts,
    int n_edges, int rsize) {
  const int range = blockIdx.x & (NRANGE - 1);
  const int chunk = blockIdx.x >> 3;
  const int lo = range * rsize;
  int base = chunk * 1024 + threadIdx.x * 4;
  if (base + 4 <= n_edges) {
    int4 dv = *(const int4*)&dst[base];
    if ((unsigned)(dv.x - lo) < (unsigned)rsize) atomicAdd(&counts[dv.x], 1);
    if ((unsigned)(dv.y - lo) < (unsigned)rsize) atomicAdd(&counts[dv.y], 1);
    if ((unsigned)(dv.z - lo) < (unsigned)rsize) atomicAdd(&counts[dv.z], 1);
    if ((unsigned)(dv.w - lo) < (unsigned)rsize) atomicAdd(&counts[dv.w], 1);
  } else {
    for (int k = 0; k < 4; ++k) {
      int e = base + k;
      if (e < n_edges) {
        int d = dst[e];
        if ((unsigned)(d - lo) < (unsigned)rsize) atomicAdd(&counts[d], 1);
      }
    }
  }
}

// ---------------------------------------------------------------------------
// 3-kernel coalesced scan: tile sums -> scan sums -> apply.
// ---------------------------------------------------------------------------
__global__ __launch_bounds__(256) void k_scan1(
    const int* __restrict__ counts, int* __restrict__ partial, int n) {
  __shared__ int s[256];
  int t = threadIdx.x;
  int i = blockIdx.x * 256 + t;
  s[t] = (i < n) ? counts[i] : 0;
  __syncthreads();
  for (int off = 128; off > 0; off >>= 1) {
    if (t < off) s[t] += s[t + off];
    __syncthreads();
  }
  if (t == 0) partial[blockIdx.x] = s[0];
}

__global__ __launch_bounds__(256) void k_scan2(int* __restrict__ partial, int nb) {
  __shared__ int s[256];
  int t = threadIdx.x;
  s[t] = (t < nb) ? partial[t] : 0;
  __syncthreads();
  for (int off = 1; off < 256; off <<= 1) {
    int v = (t >= off) ? s[t - off] : 0;
    __syncthreads();
    s[t] += v;
    __syncthreads();
  }
  if (t < nb) partial[t] = (t == 0) ? 0 : s[t - 1];
}

__global__ __launch_bounds__(256) void k_scan3(
    const int* __restrict__ counts, const int* __restrict__ partial,
    int* __restrict__ offsets, int* __restrict__ cursor, int n, int n_edges) {
  __shared__ int s[256];
  int t = threadIdx.x;
  int i = blockIdx.x * 256 + t;
  int v = (i < n) ? counts[i] : 0;
  s[t] = v;
  __syncthreads();
  for (int off = 1; off < 256; off <<= 1) {
    int u = (t >= off) ? s[t - off] : 0;
    __syncthreads();
    s[t] += u;
    __syncthreads();
  }
  int excl = s[t] - v + partial[blockIdx.x];
  if (i < n) {
    offsets[i] = excl;
    cursor[i] = excl;
  }
  if (i == 0) offsets[n] = n_edges;
}

// ---------------------------------------------------------------------------
// Reorder + softmax, XCD-bucketed like k_hist. Each block streams a
// 1024-edge chunk and scatters only records for its dst range -> the
// 1.6 MB recs slice + cursor slice stay in one XCD's L2 -> full-line
// writebacks instead of 4x-amplified partials.
// ---------------------------------------------------------------------------
__global__ __launch_bounds__(256) void k_reorder(
    const int* __restrict__ src, const int* __restrict__ dst,
    const float* __restrict__ e_src, const float* __restrict__ e_dst,
    int* __restrict__ cursor, int4* __restrict__ recs,
    int n_edges, int rsize) {
  const int range = blockIdx.x & (NRANGE - 1);
  const int chunk = blockIdx.x >> 3;
  const int lo = range * rsize;
  int base = chunk * 1024 + threadIdx.x * 4;

  int4 dv, sv;
  bool full = (base + 4 <= n_edges);
  if (full) {
    dv = *(const int4*)&dst[base];
    sv = *(const int4*)&src[base];
  } else {
    int tmpd[4], tmps[4];
    for (int k = 0; k < 4; ++k) {
      int e = base + k;
      tmpd[k] = (e < n_edges) ? dst[e] : -1;
      tmps[k] = (e < n_edges) ? src[e] : 0;
    }
    dv = make_int4(tmpd[0], tmpd[1], tmpd[2], tmpd[3]);
    sv = make_int4(tmps[0], tmps[1], tmps[2], tmps[3]);
  }

  const int ds[4] = {dv.x, dv.y, dv.z, dv.w};
  const int ss[4] = {sv.x, sv.y, sv.z, sv.w};
#pragma unroll
  for (int k = 0; k < 4; ++k) {
    int d = ds[k];
    if ((unsigned)(d - lo) >= (unsigned)rsize) continue;
    int s = ss[k];
    float4 es = ((const float4*)e_src)[s];
    float4 ed = ((const float4*)e_dst)[d];
    float v0 = es.x + ed.x, v1 = es.y + ed.y, v2 = es.z + ed.z, v3 = es.w + ed.w;
    v0 = (v0 > 0.f) ? v0 : NEG_SLOPE * v0;
    v1 = (v1 > 0.f) ? v1 : NEG_SLOPE * v1;
    v2 = (v2 > 0.f) ? v2 : NEG_SLOPE * v2;
    v3 = (v3 > 0.f) ? v3 : NEG_SLOPE * v3;
    float m = fmaxf(fmaxf(v0, v1), fmaxf(v2, v3));
    float e0 = __expf(v0 - m), e1 = __expf(v1 - m);
    float e2 = __expf(v2 - m), e3 = __expf(v3 - m);
    float inv = 1.f / (e0 + e1 + e2 + e3);
    int a01 = (int)((unsigned)f2b(e0 * inv) | ((unsigned)f2b(e1 * inv) << 16));
    int a23 = (int)((unsigned)f2b(e2 * inv) | ((unsigned)f2b(e3 * inv) << 16));
    int pos = atomicAdd(&cursor[d], 1);
    recs[pos] = make_int4(s, a01, a23, 0);
  }
}

// ---------------------------------------------------------------------------
// Gather: one wave per dst node, lane = feature. Unroll x8.
// ---------------------------------------------------------------------------
__global__ __launch_bounds__(256) void k_gather(
    const int4* __restrict__ recs, const int* __restrict__ offsets,
    const unsigned short* __restrict__ h16, float* __restrict__ out,
    int n_nodes) {
  int gid = blockIdx.x * 256 + threadIdx.x;
  int d = gid >> 6;
  int c = gid & 63;
  if (d >= n_nodes) return;
  int beg = offsets[d];
  int end = offsets[d + 1];
  const bool hiword = (c & 32) != 0;
  const unsigned shamt = (c & 16) ? 16 : 0;
  float acc = 0.f;
  int j = beg;
  for (; j + 8 <= end; j += 8) {
    int4 r[8];
    float hv[8];
#pragma unroll
    for (int k = 0; k < 8; ++k) r[k] = recs[j + k];
#pragma unroll
    for (int k = 0; k < 8; ++k) hv[k] = b2f(h16[(size_t)r[k].x * HF + c]);
#pragma unroll
    for (int k = 0; k < 8; ++k) {
      unsigned aw = (unsigned)(hiword ? r[k].z : r[k].y);
      float al = __uint_as_float(((aw >> shamt) & 0xFFFFu) << 16);
      acc = fmaf(al, hv[k], acc);
    }
  }
  for (; j < end; ++j) {
    int4 r = recs[j];
    float hv = b2f(h16[(size_t)r.x * HF + c]);
    unsigned aw = (unsigned)(hiword ? r.z : r.y);
    float al = __uint_as_float(((aw >> shamt) & 0xFFFFu) << 16);
    acc = fmaf(al, hv, acc);
  }
  out[(size_t)d * HF + c] = acc;
}

extern "C" void kernel_launch(void* const* d_in, const int* in_sizes, int n_in,
                              void* d_out, int out_size, void* d_ws, size_t ws_size,
                              hipStream_t stream) {
  const float* x = (const float*)d_in[0];
  const int* ei = (const int*)d_in[1];
  const float* W = (const float*)d_in[2];
  const float* a = (const float*)d_in[3];
  float* out = (float*)d_out;

  const int n_nodes = in_sizes[0] / IN_FEAT;   // 50000
  const int n_edges = in_sizes[1] / 2;         // 800000
  const int* src = ei;
  const int* dst = ei + n_edges;

  char* ws = (char*)d_ws;
  size_t off = 0;
  unsigned short* h16 = (unsigned short*)(ws + off); off += (size_t)n_nodes * HF * 2;  // 6.4 MB
  int4* recs = (int4*)(ws + off);         off += (size_t)n_edges * 16;                 // 12.8 MB
  float* e_src = (float*)(ws + off);      off += (size_t)n_nodes * N_HEADS * 4;        // 0.8 MB
  float* e_dst = (float*)(ws + off);      off += (size_t)n_nodes * N_HEADS * 4;        // 0.8 MB
  unsigned short* Wt = (unsigned short*)(ws + off); off += (size_t)IN_FEAT * HF * 2;   // 16 KB
  int* counts = (int*)(ws + off);         off += ((size_t)n_nodes + 16) * 4;
  int* offsets = (int*)(ws + off);        off += ((size_t)n_nodes + 16) * 4;
  int* cursor = (int*)(ws + off);         off += ((size_t)n_nodes + 16) * 4;
  int* partial = (int*)(ws + off);        off += 256 * 4;

  const int nb_nodes = (n_nodes + 255) / 256;       // 196 <= 256 (k_scan2 limit)
  const int rsize = (n_nodes + NRANGE - 1) / NRANGE; // 6250
  const int n_chunks = (n_edges + 1023) / 1024;      // 782
  const int nb_bucketed = n_chunks * NRANGE;         // 6256 blocks

  hipMemsetAsync(counts, 0, (size_t)n_nodes * 4, stream);
  k_wprep<<<IN_FEAT * HF / 256, 256, 0, stream>>>(W, Wt);
  k_hist<<<nb_bucketed, 256, 0, stream>>>(dst, counts, n_edges, rsize);
  k_gemm<<<(n_nodes + 63) / 64, 256, 0, stream>>>(
      x, Wt, a, h16, e_src, e_dst, n_nodes);
  k_scan1<<<nb_nodes, 256, 0, stream>>>(counts, partial, n_nodes);
  k_scan2<<<1, 256, 0, stream>>>(partial, nb_nodes);
  k_scan3<<<nb_nodes, 256, 0, stream>>>(counts, partial, offsets, cursor, n_nodes, n_edges);
  k_reorder<<<nb_bucketed, 256, 0, stream>>>(
      src, dst, e_src, e_dst, cursor, recs, n_edges, rsize);
  k_gather<<<(n_nodes * 64 + 255) / 256, 256, 0, stream>>>(
      recs, offsets, h16, out, n_nodes);
}